// Round 9
// baseline (962.295 us; speedup 1.0000x reference)
//
#include <hip/hip_runtime.h>

typedef unsigned short u16;
typedef unsigned int u32;
typedef short bf16x8 __attribute__((ext_vector_type(8)));
typedef float f32x4 __attribute__((ext_vector_type(4)));

#define S_LEN 500
#define NB 256
#define EDIM 128

__device__ __forceinline__ float bf2f(u16 u) { return __uint_as_float(((u32)u) << 16); }
__device__ __forceinline__ u16 f2bf(float f) {
    u32 x = __float_as_uint(f);
    x += 0x7FFFu + ((x >> 16) & 1u);   // round-to-nearest-even
    return (u16)(x >> 16);
}
// HW packed f32->bf16 (RNE, matches f2bf): 1 inst for 2 values. lo->bits[15:0].
__device__ __forceinline__ u32 cvtpk(float lo, float hi) {
    u32 r;
    asm("v_cvt_pk_bf16_f32 %0, %1, %2" : "=v"(r) : "v"(lo), "v"(hi));
    return r;
}
__device__ __forceinline__ float fexp(float x) { return __builtin_amdgcn_exp2f(x * 1.44269504089f); }
__device__ __forceinline__ float frcp(float x) { return __builtin_amdgcn_rcpf(x); }
__device__ __forceinline__ float sigm(float x) { return frcp(1.0f + fexp(-x)); }
__device__ __forceinline__ float tanh_(float x) { return 1.0f - 2.0f * frcp(1.0f + fexp(2.0f * x)); }
__device__ __forceinline__ int iclamp(int v, int hi) { return v < 0 ? 0 : (v > hi ? hi : v); }

// ---------------------------------------------------------------------------
// R1-proven workgroup sync: lane-0 atomicAdd on an LDS counter + broadcast
// poll. Measured FASTER than raw s_barrier on this kernel (1490 vs 1878 us)
// -- staggered release naturally de-synchronizes the 2 waves/SIMD bursts.
// ---------------------------------------------------------------------------
__device__ __forceinline__ void wgsync(volatile int* c, int target) {
    __asm__ volatile("s_waitcnt lgkmcnt(0)" ::: "memory");  // prior LDS writes done
    if ((threadIdx.x & 63) == 0) atomicAdd((int*)c, 1);
    while (*c < target) {}
    __asm__ volatile("" ::: "memory");
}

// ---------------------------------------------------------------------------
// Runtime float-dtype detection from q_embedding bit patterns (wave-uniform).
// ---------------------------------------------------------------------------
__device__ __forceinline__ bool detect_bf16(const void* q) {
    const u16* w = (const u16*)q;
    int plaus = 0;
#pragma unroll 1
    for (int i = 0; i < 64; ++i) {
        const u16 v = w[2 * i];
        const int e = (v >> 7) & 0xFF;
        plaus += (v == 0 || (e >= 100 && e <= 130)) ? 1 : 0;
    }
    return plaus >= 48;
}
__device__ __forceinline__ float ldF(const void* p, int i, bool bf) {
    return bf ? bf2f(((const u16*)p)[i]) : ((const float*)p)[i];
}
template <bool BF>
__device__ __forceinline__ bf16x8 ldfragT(const void* p, int i) {
    if (BF) return *(const bf16x8*)((const u16*)p + i);
    const float* f = (const float*)p + i;
    bf16x8 r;
#pragma unroll
    for (int e = 0; e < 8; ++e) r[e] = (short)f2bf(f[e]);
    return r;
}
// runtime-dtype fragment loader (wave-uniform bf flag)
__device__ __forceinline__ bf16x8 ldfragR(const void* p, int i, bool bf) {
    if (bf) return *(const bf16x8*)((const u16*)p + i);
    const float* f = (const float*)p + i;
    bf16x8 r;
#pragma unroll
    for (int e = 0; e < 8; ++e) r[e] = (short)f2bf(f[e]);
    return r;
}

__global__ void dimkt_sentinel(u16* __restrict__ out, u16 val) {
    out[blockIdx.x * 256 + threadIdx.x] = val;
}

// ---------------------------------------------------------------------------
// K-conv: one-time q_emb f32 -> bf16 (guarded: no-op when input is bf16).
// ---------------------------------------------------------------------------
__global__ void dimkt_qe16(const float* __restrict__ qf, u16* __restrict__ qe16) {
    if (detect_bf16(qf)) return;
    const int i = (blockIdx.x * 256 + threadIdx.x) * 8;
    const float4 a = *(const float4*)(qf + i);
    const float4 b = *(const float4*)(qf + i + 4);
    ushort4 lo, hi;
    lo.x = f2bf(a.x); lo.y = f2bf(a.y); lo.z = f2bf(a.z); lo.w = f2bf(a.w);
    hi.x = f2bf(b.x); hi.y = f2bf(b.y); hi.z = f2bf(b.z); hi.w = f2bf(b.w);
    *(ushort4*)(qe16 + i) = lo;
    *(ushort4*)(qe16 + i + 4) = hi;
}

// K-conv: W1 -> bf16 (or copy if already bf16). 128*512 = 65,536 elems.
__global__ void dimkt_w1bf(const void* __restrict__ W1, const void* __restrict__ qref,
                           u16* __restrict__ W1b) {
    const bool bf = detect_bf16(qref);
    const int i = blockIdx.x * 256 + threadIdx.x;
    W1b[i] = bf ? ((const u16*)W1)[i] : f2bf(((const float*)W1)[i]);
}

// ---------------------------------------------------------------------------
// K0: tiny gather-table precompute. Layout (per-col scalar):
//   cW1p[cx*128 + col] ; sdQ/qdQ[x*256 + col*2 + {0:W1,1:W6}]
//   aW6p[ax*128 + col] (+b6) ; c4t/c5t[ax*128 + col] (+b4/+b5)
// ---------------------------------------------------------------------------
__global__ void dimkt_tabs(const void* __restrict__ q_emb,
                           const void* __restrict__ c_tab, const void* __restrict__ sd_tab,
                           const void* __restrict__ qd_tab, const void* __restrict__ a_tab,
                           const void* __restrict__ W1, const void* __restrict__ W4,
                           const void* __restrict__ W5, const void* __restrict__ W6,
                           const void* __restrict__ b4, const void* __restrict__ b5,
                           const void* __restrict__ b6,
                           float* __restrict__ cW1p, float* __restrict__ sdQ,
                           float* __restrict__ qdQ, float* __restrict__ aW6p,
                           float* __restrict__ c4t, float* __restrict__ c5t) {
    const bool bf = detect_bf16(q_emb);
    __shared__ float src[128];
    const int r = blockIdx.x, n = threadIdx.x;
    const void* srcp; const void* W; const void* bias = nullptr;
    int soff, koff, ld, oidx; float* outp; bool mask;
    if (r < 1001)      { srcp = c_tab;  soff = r * 128;               W = W1; koff = 128; ld = 512; outp = cW1p; oidx = r * 128 + n;           mask = (r == 0); }
    else if (r < 1103) { int rr = r - 1001; srcp = sd_tab; soff = rr * 128; W = W1; koff = 256; ld = 512; outp = sdQ;  oidx = rr * 256 + n * 2;     mask = (rr == 0); }
    else if (r < 1205) { int rr = r - 1103; srcp = qd_tab; soff = rr * 128; W = W1; koff = 384; ld = 512; outp = qdQ;  oidx = rr * 256 + n * 2;     mask = (rr == 0); }
    else if (r < 1307) { int rr = r - 1205; srcp = sd_tab; soff = rr * 128; W = W6; koff = 256; ld = 512; outp = sdQ;  oidx = rr * 256 + n * 2 + 1; mask = (rr == 0); }
    else if (r < 1409) { int rr = r - 1307; srcp = qd_tab; soff = rr * 128; W = W6; koff = 384; ld = 512; outp = qdQ;  oidx = rr * 256 + n * 2 + 1; mask = (rr == 0); }
    else if (r < 1411) { int rr = r - 1409; srcp = a_tab;  soff = rr * 128; W = W6; koff = 128; ld = 512; outp = aW6p; oidx = rr * 128 + n;         bias = b6; mask = false; }
    else if (r < 1413) { int rr = r - 1411; srcp = a_tab;  soff = rr * 128; W = W4; koff = 128; ld = 256; outp = c4t;  oidx = rr * 128 + n;         bias = b4; mask = false; }
    else               { int rr = r - 1413; srcp = a_tab;  soff = rr * 128; W = W5; koff = 128; ld = 256; outp = c5t;  oidx = rr * 128 + n;         bias = b5; mask = false; }
    src[n] = ldF(srcp, soff + n, bf);
    __syncthreads();
    float acc = 0.f;
    if (!mask) {
        if (bf) {
            const u16* Wp = (const u16*)W + n * ld + koff;
#pragma unroll 4
            for (int k = 0; k < 128; k += 8) {
                const ushort4 wa = *(const ushort4*)(Wp + k);
                const ushort4 wb = *(const ushort4*)(Wp + k + 4);
                acc += src[k] * bf2f(wa.x) + src[k + 1] * bf2f(wa.y)
                     + src[k + 2] * bf2f(wa.z) + src[k + 3] * bf2f(wa.w)
                     + src[k + 4] * bf2f(wb.x) + src[k + 5] * bf2f(wb.y)
                     + src[k + 6] * bf2f(wb.z) + src[k + 7] * bf2f(wb.w);
            }
        } else {
            const float* Wp = (const float*)W + n * ld + koff;
#pragma unroll 4
            for (int k = 0; k < 128; k += 4) {
                const float4 w4 = *(const float4*)(Wp + k);
                acc += src[k] * w4.x + src[k + 1] * w4.y + src[k + 2] * w4.z + src[k + 3] * w4.w;
            }
        }
        if (bias) acc += ldF(bias, n, bf);
    }
    outp[oidx] = acc;
}

// ---------------------------------------------------------------------------
// K1: INP(+Z6) precompute. pk=1: store u32 {inp(bf16 lo), z6(bf16 hi)} in
// BLOCK-COALESCED layout INPZ6T[((t*16+rc)*128+col)*16 + row_in_block]:
// per store instruction the wave writes 1KB CONTIGUOUS (R8's [t][col][row]
// layout scattered each lane's 16B 1KB apart -> ~4x write amplification).
// The scan's per-wave read of the same block is also 1KB contiguous.
// pk=0: R6-style bf16 INP16 row-major.
// ---------------------------------------------------------------------------
__global__ void dimkt_inp(const void* __restrict__ q_emb, const u16* __restrict__ qe16,
                          const u16* __restrict__ W1b, const int fastpath,
                          const void* __restrict__ W1, const void* __restrict__ b1,
                          const int* __restrict__ cI, const int* __restrict__ sI,
                          const int* __restrict__ qI, const int* __restrict__ aI,
                          const float* __restrict__ cW1p, const float* __restrict__ sdQ,
                          const float* __restrict__ qdQ, const float* __restrict__ aW6p,
                          u16* __restrict__ INP16, u32* __restrict__ INPZ6T, const int pk) {
    const bool bf = detect_bf16(q_emb);
    const int t = blockIdx.x, rc = blockIdx.y;
    const int lane = threadIdx.x, quad = lane >> 4, l15 = lane & 15;
    const bool fA = bf || (fastpath != 0);
    const u16* aes = bf ? (const u16*)q_emb : qe16;
    bf16x8 ae[4];
#pragma unroll
    for (int ks = 0; ks < 4; ++ks) {
        const int off = ((rc * 16 + l15) * S_LEN + t) * EDIM + ks * 32 + quad * 8;
        ae[ks] = fA ? *(const bf16x8*)(aes + off) : ldfragR(q_emb, off, false);
    }
    int cx[4], sx[4], qx[4], ax[4];
#pragma unroll
    for (int i = 0; i < 4; ++i) {
        const int off = (rc * 16 + quad * 4 + i) * S_LEN + t;
        cx[i] = iclamp(cI[off], 1000);
        sx[i] = iclamp(sI[off], 101);
        qx[i] = iclamp(qI[off], 101);
        ax[i] = iclamp(aI[off], 1);
    }
#pragma unroll 1
    for (int ct = 0; ct < 8; ++ct) {
        const int colc = ct * 16 + l15;
        bf16x8 w[4];
#pragma unroll
        for (int ks = 0; ks < 4; ++ks) {
            const int woff = colc * 512 + ks * 32 + quad * 8;
            w[ks] = fastpath ? *(const bf16x8*)(W1b + woff) : ldfragR(W1, woff, bf);
        }
        const float b1c = ldF(b1, colc, bf);
        f32x4 acc; float z6v[4];
#pragma unroll
        for (int i = 0; i < 4; ++i) {
            const float2 sgp = *(const float2*)(sdQ + sx[i] * 256 + colc * 2);
            const float2 qgp = *(const float2*)(qdQ + qx[i] * 256 + colc * 2);
            acc[i] = b1c + cW1p[cx[i] * 128 + colc] + sgp.x + qgp.x;
            z6v[i] = pk ? (aW6p[ax[i] * 128 + colc] + sgp.y + qgp.y) : 0.f;
        }
#pragma unroll
        for (int ks = 0; ks < 4; ++ks)
            acc = __builtin_amdgcn_mfma_f32_16x16x32_bf16(ae[ks], w[ks], acc, 0, 0, 0);
        if (pk) {
            uint4 st;
            st.x = cvtpk(acc[0], z6v[0]); st.y = cvtpk(acc[1], z6v[1]);
            st.z = cvtpk(acc[2], z6v[2]); st.w = cvtpk(acc[3], z6v[3]);
            *(uint4*)(INPZ6T + (((size_t)t * 16 + rc) * 128 + colc) * 16 + quad * 4) = st;
        } else {
#pragma unroll
            for (int i = 0; i < 4; ++i)
                INP16[((size_t)t * 256 + rc * 16 + quad * 4 + i) * 128 + colc] = f2bf(acc[i]);
        }
    }
}

// ---------------------------------------------------------------------------
// K2-PK: fused 500-step scan, packed-input form. 16 WGs x 512 threads.
// R9 changes: block-coalesced INPZ6T read (matches new inp layout; wave
// reads 1KB contiguous); a-bits packed ONCE into LDS u16[500] bitmask
// (1 broadcast ds_read + bfe per step replaces 4 global loads + clamps).
// ---------------------------------------------------------------------------
template <bool BF>
__global__ __launch_bounds__(512, 2) void dimkt_scan_pk(
    const void* __restrict__ q_emb, const u32* __restrict__ INPZ6T,
    const int* __restrict__ aI,
    const void* __restrict__ W2, const void* __restrict__ b2,
    const void* __restrict__ W3, const void* __restrict__ b3,
    const void* __restrict__ W4, const void* __restrict__ W5,
    const void* __restrict__ W6, const void* __restrict__ knowledge,
    const float* __restrict__ c4t, const float* __restrict__ c5t,
    void* __restrict__ outv) {
    if (detect_bf16(q_emb) != BF) return;   // wrong specialization: uniform exit
    __shared__ __align__(16) u16 kbuf[16][136];
    __shared__ __align__(16) u16 qqbuf[16][136];
    __shared__ __align__(16) u16 sdbuf[16][136];
    __shared__ u16 aBits[S_LEN];   // bit r of aBits[t] = a-flag of row b0+r at t
    __shared__ int sctr;

    const int tid = threadIdx.x;
    const int wv = tid >> 6, lane = tid & 63;
    const int quad = lane >> 4, l15 = lane & 15;
    const int b0 = blockIdx.x * 16;
    const int col = wv * 16 + l15;
    const int quadX = quad ^ (l15 >> 2);   // read-side swizzled chunk index
    const int wcolX = col ^ (quad << 3);   // write-side swizzled column

    // ---- stationary weight fragments (registers, 500-step resident) ----
    bf16x8 fW2[4], fW3[4], fW4[4], fW5[4], fW6[4];
#pragma unroll
    for (int ks = 0; ks < 4; ++ks) {
        const int ko = ks * 32 + quad * 8;
        fW2[ks] = ldfragT<BF>(W2, col * 128 + ko);
        fW3[ks] = ldfragT<BF>(W3, col * 128 + ko);
        fW4[ks] = ldfragT<BF>(W4, col * 256 + ko);   // W4[:, :128]
        fW5[ks] = ldfragT<BF>(W5, col * 256 + ko);   // W5[:, :128]
        fW6[ks] = ldfragT<BF>(W6, col * 512 + ko);   // W6[:, :128]
    }
    const float b2v = ldF(b2, col, BF);
    const float b3v = ldF(b3, col, BF);
    const float c4_0 = c4t[col], c4_1 = c4t[128 + col];
    const float c5_0 = c5t[col], c5_1 = c5t[128 + col];

    // block-coalesced stream: base of this WG's (col, 4-row) lane within t=0
    const u32* pzBase = INPZ6T + (((size_t)blockIdx.x) * 128 + col) * 16 + quad * 4;

    // ---- pack a-bits into LDS bitmask (one-time; coalesced per row) ----
#pragma unroll 1
    for (int tt = tid; tt < S_LEN; tt += 512) {
        u32 bits = 0;
#pragma unroll
        for (int r = 0; r < 16; ++r)
            bits |= (u32)iclamp(aI[(b0 + r) * S_LEN + tt], 1) << r;
        aBits[tt] = (u16)bits;
    }

    // ---- t=0 init ----
    float kold[4], z6c[4], g[4];
    int ac[4];
    {
        const float k0 = ldF(knowledge, col, BF);
        const u16 k0b = f2bf(k0);
        const uint4 pz0 = *(const uint4*)pzBase;
        const u32 pzv[4] = {pz0.x, pz0.y, pz0.z, pz0.w};
        if (tid == 0) sctr = 0;
#pragma unroll
        for (int i = 0; i < 4; ++i) {
            ac[i] = iclamp(aI[(b0 + quad * 4 + i) * S_LEN], 1);
            z6c[i] = __uint_as_float(pzv[i] & 0xFFFF0000u);
            const float inp0 = __uint_as_float(pzv[i] << 16);
            kold[i] = k0;
            kbuf[quad * 4 + i][wcolX] = k0b;
            qqbuf[quad * 4 + i][wcolX] = f2bf(k0 - inp0);
        }
    }
    __syncthreads();   // one real barrier pre-loop (aBits/kbuf/qqbuf published)

    const u32* pzP = pzBase + 32768;   // {inp,z6} stream, t+1 (stride 16*128*16)
    int bar = 0;
#pragma unroll 1
    for (int t = 0; t < S_LEN - 1; ++t) {
        // ---- prefetch t+1: packed {inp,z6} (1KB-coalesced per wave) + a-bits
        const u32 ab = aBits[t + 1];
        int an[4];
#pragma unroll
        for (int i = 0; i < 4; ++i) an[i] = (ab >> (quad * 4 + i)) & 1;
        const uint4 pzN = *(const uint4*)pzP;
        pzP += 32768;

        // ---- phase B: Y2/Y3 on qq, Y6 on k; sdft -> LDS ----
        bf16x8 aq[4], ak[4];
#pragma unroll
        for (int ks = 0; ks < 4; ++ks) {
            aq[ks] = *(const bf16x8*)&qqbuf[l15][ks * 32 + quadX * 8];
            ak[ks] = *(const bf16x8*)&kbuf[l15][ks * 32 + quadX * 8];
        }
        f32x4 Y2 = (f32x4){b2v, b2v, b2v, b2v};
        f32x4 Y3 = (f32x4){b3v, b3v, b3v, b3v};
        f32x4 Y6 = (f32x4){z6c[0], z6c[1], z6c[2], z6c[3]};
#pragma unroll
        for (int ks = 0; ks < 4; ++ks) {
            Y2 = __builtin_amdgcn_mfma_f32_16x16x32_bf16(aq[ks], fW2[ks], Y2, 0, 0, 0);
            Y3 = __builtin_amdgcn_mfma_f32_16x16x32_bf16(aq[ks], fW3[ks], Y3, 0, 0, 0);
            Y6 = __builtin_amdgcn_mfma_f32_16x16x32_bf16(ak[ks], fW6[ks], Y6, 0, 0, 0);
        }
        float sdv[4];
#pragma unroll
        for (int i = 0; i < 4; ++i) sdv[i] = sigm(Y2[i]) * tanh_(Y3[i]);
        {
            const u32 s01 = cvtpk(sdv[0], sdv[1]), s23 = cvtpk(sdv[2], sdv[3]);
            sdbuf[quad * 4 + 0][wcolX] = (u16)s01;
            sdbuf[quad * 4 + 1][wcolX] = (u16)(s01 >> 16);
            sdbuf[quad * 4 + 2][wcolX] = (u16)s23;
            sdbuf[quad * 4 + 3][wcolX] = (u16)(s23 >> 16);
        }
        bar += 8; wgsync(&sctr, bar);

        // ---- phase C: Y4/Y5 on sdft; g; k update; write k/qq for t+1 ----
        bf16x8 as[4];
#pragma unroll
        for (int ks = 0; ks < 4; ++ks)
            as[ks] = *(const bf16x8*)&sdbuf[l15][ks * 32 + quadX * 8];
#pragma unroll
        for (int i = 0; i < 4; ++i) g[i] = sigm(Y6[i]);
        f32x4 Y4 = (f32x4){ac[0] ? c4_1 : c4_0, ac[1] ? c4_1 : c4_0,
                           ac[2] ? c4_1 : c4_0, ac[3] ? c4_1 : c4_0};
        f32x4 Y5 = (f32x4){ac[0] ? c5_1 : c5_0, ac[1] ? c5_1 : c5_0,
                           ac[2] ? c5_1 : c5_0, ac[3] ? c5_1 : c5_0};
#pragma unroll
        for (int ks = 0; ks < 4; ++ks) {
            Y4 = __builtin_amdgcn_mfma_f32_16x16x32_bf16(as[ks], fW4[ks], Y4, 0, 0, 0);
            Y5 = __builtin_amdgcn_mfma_f32_16x16x32_bf16(as[ks], fW5[ks], Y5, 0, 0, 0);
        }
        const u32 pzv[4] = {pzN.x, pzN.y, pzN.z, pzN.w};
        float knA[4], qqA[4];
#pragma unroll
        for (int i = 0; i < 4; ++i) {
            const float pk = sigm(Y4[i]) * tanh_(Y5[i]);
            const float kn = g[i] * kold[i] + (1.0f - g[i]) * pk;
            kold[i] = kn; knA[i] = kn;
            qqA[i] = kn - __uint_as_float(pzv[i] << 16);    // qq_{t+1} = k - inp_{t+1}
        }
        {
            const u32 k01 = cvtpk(knA[0], knA[1]), k23 = cvtpk(knA[2], knA[3]);
            const u32 q01 = cvtpk(qqA[0], qqA[1]), q23 = cvtpk(qqA[2], qqA[3]);
            kbuf[quad * 4 + 0][wcolX] = (u16)k01;
            kbuf[quad * 4 + 1][wcolX] = (u16)(k01 >> 16);
            kbuf[quad * 4 + 2][wcolX] = (u16)k23;
            kbuf[quad * 4 + 3][wcolX] = (u16)(k23 >> 16);
            qqbuf[quad * 4 + 0][wcolX] = (u16)q01;
            qqbuf[quad * 4 + 1][wcolX] = (u16)(q01 >> 16);
            qqbuf[quad * 4 + 2][wcolX] = (u16)q23;
            qqbuf[quad * 4 + 3][wcolX] = (u16)(q23 >> 16);
        }
        // ---- rotate: z6/ac for t+1 (straight from packed load) ----
#pragma unroll
        for (int i = 0; i < 4; ++i) {
            z6c[i] = __uint_as_float(pzv[i] & 0xFFFF0000u);
            ac[i] = an[i];
        }
        bar += 8; wgsync(&sctr, bar);
    }

    // ---- peeled final step (t = S_LEN-1): no prefetch, no next-state
    //      writes, no trailing sync (epilogue is thread-local) ----
    {
        bf16x8 aq[4], ak[4];
#pragma unroll
        for (int ks = 0; ks < 4; ++ks) {
            aq[ks] = *(const bf16x8*)&qqbuf[l15][ks * 32 + quadX * 8];
            ak[ks] = *(const bf16x8*)&kbuf[l15][ks * 32 + quadX * 8];
        }
        f32x4 Y2 = (f32x4){b2v, b2v, b2v, b2v};
        f32x4 Y3 = (f32x4){b3v, b3v, b3v, b3v};
        f32x4 Y6 = (f32x4){z6c[0], z6c[1], z6c[2], z6c[3]};
#pragma unroll
        for (int ks = 0; ks < 4; ++ks) {
            Y2 = __builtin_amdgcn_mfma_f32_16x16x32_bf16(aq[ks], fW2[ks], Y2, 0, 0, 0);
            Y3 = __builtin_amdgcn_mfma_f32_16x16x32_bf16(aq[ks], fW3[ks], Y3, 0, 0, 0);
            Y6 = __builtin_amdgcn_mfma_f32_16x16x32_bf16(ak[ks], fW6[ks], Y6, 0, 0, 0);
        }
        float sdv[4];
#pragma unroll
        for (int i = 0; i < 4; ++i) sdv[i] = sigm(Y2[i]) * tanh_(Y3[i]);
        {
            const u32 s01 = cvtpk(sdv[0], sdv[1]), s23 = cvtpk(sdv[2], sdv[3]);
            sdbuf[quad * 4 + 0][wcolX] = (u16)s01;
            sdbuf[quad * 4 + 1][wcolX] = (u16)(s01 >> 16);
            sdbuf[quad * 4 + 2][wcolX] = (u16)s23;
            sdbuf[quad * 4 + 3][wcolX] = (u16)(s23 >> 16);
        }
        bar += 8; wgsync(&sctr, bar);

        bf16x8 as[4];
#pragma unroll
        for (int ks = 0; ks < 4; ++ks)
            as[ks] = *(const bf16x8*)&sdbuf[l15][ks * 32 + quadX * 8];
#pragma unroll
        for (int i = 0; i < 4; ++i) g[i] = sigm(Y6[i]);
        f32x4 Y4 = (f32x4){ac[0] ? c4_1 : c4_0, ac[1] ? c4_1 : c4_0,
                           ac[2] ? c4_1 : c4_0, ac[3] ? c4_1 : c4_0};
        f32x4 Y5 = (f32x4){ac[0] ? c5_1 : c5_0, ac[1] ? c5_1 : c5_0,
                           ac[2] ? c5_1 : c5_0, ac[3] ? c5_1 : c5_0};
#pragma unroll
        for (int ks = 0; ks < 4; ++ks) {
            Y4 = __builtin_amdgcn_mfma_f32_16x16x32_bf16(as[ks], fW4[ks], Y4, 0, 0, 0);
            Y5 = __builtin_amdgcn_mfma_f32_16x16x32_bf16(as[ks], fW5[ks], Y5, 0, 0, 0);
        }
#pragma unroll
        for (int i = 0; i < 4; ++i) {
            const float pk = sigm(Y4[i]) * tanh_(Y5[i]);
            kold[i] = g[i] * kold[i] + (1.0f - g[i]) * pk;
        }
    }

    // ---- epilogue: out = sigmoid(k_final), [B][E], dtype matches input ----
#pragma unroll
    for (int i = 0; i < 4; ++i) {
        const int row = quad * 4 + i;
        const float v = sigm(kold[i]);
        const int off = (b0 + row) * EDIM + col;
        if (BF) ((u16*)outv)[off] = f2bf(v);
        else    ((float*)outv)[off] = v;
    }
}

// ---------------------------------------------------------------------------
// K2-FB: R6 scan, verbatim (fallback when ws can't hold INPZ6T).
// ---------------------------------------------------------------------------
template <bool BF>
__global__ __launch_bounds__(512, 2) void dimkt_scan_fb(
    const void* __restrict__ q_emb, const u16* __restrict__ INP16,
    const int* __restrict__ cI, const int* __restrict__ sI,
    const int* __restrict__ qI, const int* __restrict__ aI,
    const void* __restrict__ W2, const void* __restrict__ b2,
    const void* __restrict__ W3, const void* __restrict__ b3,
    const void* __restrict__ W4, const void* __restrict__ W5,
    const void* __restrict__ W6, const void* __restrict__ knowledge,
    const float* __restrict__ sdQ, const float* __restrict__ qdQ,
    const float* __restrict__ aW6p, const float* __restrict__ c4t,
    const float* __restrict__ c5t, void* __restrict__ outv) {
    if (detect_bf16(q_emb) != BF) return;
    __shared__ __align__(16) u16 kbuf[16][136];
    __shared__ __align__(16) u16 qqbuf[16][136];
    __shared__ __align__(16) u16 sdbuf[16][136];
    __shared__ u32 idxL[16][S_LEN];
    __shared__ int sctr;
    extern __shared__ __align__(16) u16 dynLDS[];
    u16* sdT = dynLDS;
    u16* qdT = dynLDS + 102 * 130;
    float* aW6L = (float*)(dynLDS + 2 * 102 * 130);

    const int tid = threadIdx.x;
    const int wv = tid >> 6, lane = tid & 63;
    const int quad = lane >> 4, l15 = lane & 15;
    const int b0 = blockIdx.x * 16;
    const int col = wv * 16 + l15;
    const int col2 = col * 2;

    bf16x8 fW2[4], fW3[4], fW4[4], fW5[4], fW6[4];
#pragma unroll
    for (int ks = 0; ks < 4; ++ks) {
        const int ko = ks * 32 + quad * 8;
        fW2[ks] = ldfragT<BF>(W2, col * 128 + ko);
        fW3[ks] = ldfragT<BF>(W3, col * 128 + ko);
        fW4[ks] = ldfragT<BF>(W4, col * 256 + ko);
        fW5[ks] = ldfragT<BF>(W5, col * 256 + ko);
        fW6[ks] = ldfragT<BF>(W6, col * 512 + ko);
    }
    const float b2v = ldF(b2, col, BF);
    const float b3v = ldF(b3, col, BF);
    const float c4_0 = c4t[col], c4_1 = c4t[128 + col];
    const float c5_0 = c5t[col], c5_1 = c5t[128 + col];

#pragma unroll 1
    for (int r = 0; r < 16; ++r)
#pragma unroll 1
        for (int t = tid; t < S_LEN; t += 512) {
            const int off = (b0 + r) * S_LEN + t;
            idxL[r][t] = (u32)iclamp(cI[off], 1000)
                       | ((u32)iclamp(sI[off], 101) << 10)
                       | ((u32)iclamp(qI[off], 101) << 17)
                       | ((u32)iclamp(aI[off], 1) << 24);
        }
#pragma unroll 1
    for (int v = tid; v < 102 * 128; v += 512) {
        const int sx = v >> 7, cc = v & 127;
        sdT[sx * 130 + cc] = f2bf(sdQ[sx * 256 + cc * 2 + 1]);
        qdT[sx * 130 + cc] = f2bf(qdQ[sx * 256 + cc * 2 + 1]);
    }
    if (tid < 256) {
        const int rr = tid >> 7, cc = tid & 127;
        aW6L[rr * 132 + cc] = aW6p[rr * 128 + cc];
    }
    if (tid == 0) sctr = 0;
    __syncthreads();

    float kold[4], z6c[4], g[4];
    int ac[4];
    {
        const float k0 = ldF(knowledge, col, BF);
        const u16 k0b = f2bf(k0);
#pragma unroll
        for (int i = 0; i < 4; ++i) {
            const u32 p = idxL[quad * 4 + i][0];
            const int sx = (p >> 10) & 127, qx = (p >> 17) & 127, ax = (p >> 24) & 1;
            ac[i] = ax;
            const float2 sgp = *(const float2*)(sdQ + sx * 256 + col2);
            const float2 qgp = *(const float2*)(qdQ + qx * 256 + col2);
            z6c[i] = aW6p[ax * 128 + col] + sgp.y + qgp.y;
            const float inp0 = bf2f(INP16[(size_t)(b0 + quad * 4 + i) * 128 + col]);
            kold[i] = k0;
            kbuf[quad * 4 + i][col] = k0b;
            qqbuf[quad * 4 + i][col] = f2bf(k0 - inp0);
        }
    }
    u32 pk4[4];
#pragma unroll
    for (int i = 0; i < 4; ++i) pk4[i] = idxL[quad * 4 + i][1];
    __syncthreads();

    int bar = 0;
#pragma unroll 1
    for (int t = 0; t < S_LEN; ++t) {
        const int tf2 = (t + 2 < S_LEN) ? t + 2 : S_LEN - 1;
        const int tp = (t + 1 < S_LEN) ? t + 1 : S_LEN - 1;
        int an[4];
        u16 inpN[4];
        float sw6[4], qw6[4], agv[4];
#pragma unroll
        for (int i = 0; i < 4; ++i) {
            const u32 p = pk4[i];
            const int sx = (p >> 10) & 127, qx = (p >> 17) & 127;
            an[i] = (p >> 24) & 1;
            inpN[i] = INP16[((size_t)tp * 256 + b0 + quad * 4 + i) * 128 + col];
            sw6[i] = bf2f(sdT[sx * 130 + col]);
            qw6[i] = bf2f(qdT[qx * 130 + col]);
            agv[i] = aW6L[an[i] * 132 + col];
        }
#pragma unroll
        for (int i = 0; i < 4; ++i) pk4[i] = idxL[quad * 4 + i][tf2];

        bf16x8 aq[4], ak[4];
#pragma unroll
        for (int ks = 0; ks < 4; ++ks) {
            aq[ks] = *(const bf16x8*)&qqbuf[l15][ks * 32 + quad * 8];
            ak[ks] = *(const bf16x8*)&kbuf[l15][ks * 32 + quad * 8];
        }
        f32x4 Y2a = (f32x4){b2v, b2v, b2v, b2v}, Y2b = (f32x4){0.f, 0.f, 0.f, 0.f};
        f32x4 Y3a = (f32x4){b3v, b3v, b3v, b3v}, Y3b = (f32x4){0.f, 0.f, 0.f, 0.f};
        f32x4 Y6a = (f32x4){z6c[0], z6c[1], z6c[2], z6c[3]}, Y6b = (f32x4){0.f, 0.f, 0.f, 0.f};
        Y2a = __builtin_amdgcn_mfma_f32_16x16x32_bf16(aq[0], fW2[0], Y2a, 0, 0, 0);
        Y3a = __builtin_amdgcn_mfma_f32_16x16x32_bf16(aq[0], fW3[0], Y3a, 0, 0, 0);
        Y6a = __builtin_amdgcn_mfma_f32_16x16x32_bf16(ak[0], fW6[0], Y6a, 0, 0, 0);
        Y2b = __builtin_amdgcn_mfma_f32_16x16x32_bf16(aq[2], fW2[2], Y2b, 0, 0, 0);
        Y3b = __builtin_amdgcn_mfma_f32_16x16x32_bf16(aq[2], fW3[2], Y3b, 0, 0, 0);
        Y6b = __builtin_amdgcn_mfma_f32_16x16x32_bf16(ak[2], fW6[2], Y6b, 0, 0, 0);
        Y2a = __builtin_amdgcn_mfma_f32_16x16x32_bf16(aq[1], fW2[1], Y2a, 0, 0, 0);
        Y3a = __builtin_amdgcn_mfma_f32_16x16x32_bf16(aq[1], fW3[1], Y3a, 0, 0, 0);
        Y6a = __builtin_amdgcn_mfma_f32_16x16x32_bf16(ak[1], fW6[1], Y6a, 0, 0, 0);
        Y2b = __builtin_amdgcn_mfma_f32_16x16x32_bf16(aq[3], fW2[3], Y2b, 0, 0, 0);
        Y3b = __builtin_amdgcn_mfma_f32_16x16x32_bf16(aq[3], fW3[3], Y3b, 0, 0, 0);
        Y6b = __builtin_amdgcn_mfma_f32_16x16x32_bf16(ak[3], fW6[3], Y6b, 0, 0, 0);
        const f32x4 Y2 = Y2a + Y2b, Y3 = Y3a + Y3b, Y6 = Y6a + Y6b;
        float sdv[4];
#pragma unroll
        for (int i = 0; i < 4; ++i) sdv[i] = sigm(Y2[i]) * tanh_(Y3[i]);
        {
            const u32 s01 = cvtpk(sdv[0], sdv[1]), s23 = cvtpk(sdv[2], sdv[3]);
            sdbuf[quad * 4 + 0][col] = (u16)s01;
            sdbuf[quad * 4 + 1][col] = (u16)(s01 >> 16);
            sdbuf[quad * 4 + 2][col] = (u16)s23;
            sdbuf[quad * 4 + 3][col] = (u16)(s23 >> 16);
        }
        bar += 8; wgsync(&sctr, bar);

        bf16x8 as[4];
#pragma unroll
        for (int ks = 0; ks < 4; ++ks)
            as[ks] = *(const bf16x8*)&sdbuf[l15][ks * 32 + quad * 8];
#pragma unroll
        for (int i = 0; i < 4; ++i) g[i] = sigm(Y6[i]);
        f32x4 Y4a = (f32x4){ac[0] ? c4_1 : c4_0, ac[1] ? c4_1 : c4_0,
                            ac[2] ? c4_1 : c4_0, ac[3] ? c4_1 : c4_0};
        f32x4 Y5a = (f32x4){ac[0] ? c5_1 : c5_0, ac[1] ? c5_1 : c5_0,
                            ac[2] ? c5_1 : c5_0, ac[3] ? c5_1 : c5_0};
        f32x4 Y4b = (f32x4){0.f, 0.f, 0.f, 0.f}, Y5b = (f32x4){0.f, 0.f, 0.f, 0.f};
        Y4a = __builtin_amdgcn_mfma_f32_16x16x32_bf16(as[0], fW4[0], Y4a, 0, 0, 0);
        Y5a = __builtin_amdgcn_mfma_f32_16x16x32_bf16(as[0], fW5[0], Y5a, 0, 0, 0);
        Y4b = __builtin_amdgcn_mfma_f32_16x16x32_bf16(as[2], fW4[2], Y4b, 0, 0, 0);
        Y5b = __builtin_amdgcn_mfma_f32_16x16x32_bf16(as[2], fW5[2], Y5b, 0, 0, 0);
        Y4a = __builtin_amdgcn_mfma_f32_16x16x32_bf16(as[1], fW4[1], Y4a, 0, 0, 0);
        Y5a = __builtin_amdgcn_mfma_f32_16x16x32_bf16(as[1], fW5[1], Y5a, 0, 0, 0);
        Y4b = __builtin_amdgcn_mfma_f32_16x16x32_bf16(as[3], fW4[3], Y4b, 0, 0, 0);
        Y5b = __builtin_amdgcn_mfma_f32_16x16x32_bf16(as[3], fW5[3], Y5b, 0, 0, 0);
        const f32x4 Y4 = Y4a + Y4b, Y5 = Y5a + Y5b;
        float knA[4], qqA[4];
#pragma unroll
        for (int i = 0; i < 4; ++i) {
            const float pk = sigm(Y4[i]) * tanh_(Y5[i]);
            const float kn = g[i] * kold[i] + (1.0f - g[i]) * pk;
            kold[i] = kn; knA[i] = kn;
            qqA[i] = kn - bf2f(inpN[i]);
        }
        {
            const u32 k01 = cvtpk(knA[0], knA[1]), k23 = cvtpk(knA[2], knA[3]);
            const u32 q01 = cvtpk(qqA[0], qqA[1]), q23 = cvtpk(qqA[2], qqA[3]);
            kbuf[quad * 4 + 0][col] = (u16)k01;
            kbuf[quad * 4 + 1][col] = (u16)(k01 >> 16);
            kbuf[quad * 4 + 2][col] = (u16)k23;
            kbuf[quad * 4 + 3][col] = (u16)(k23 >> 16);
            qqbuf[quad * 4 + 0][col] = (u16)q01;
            qqbuf[quad * 4 + 1][col] = (u16)(q01 >> 16);
            qqbuf[quad * 4 + 2][col] = (u16)q23;
            qqbuf[quad * 4 + 3][col] = (u16)(q23 >> 16);
        }
#pragma unroll
        for (int i = 0; i < 4; ++i) {
            z6c[i] = agv[i] + sw6[i] + qw6[i];
            ac[i] = an[i];
        }
        bar += 8; wgsync(&sctr, bar);
    }

#pragma unroll
    for (int i = 0; i < 4; ++i) {
        const int row = quad * 4 + i;
        const float v = sigm(kold[i]);
        const int off = (b0 + row) * EDIM + col;
        if (BF) ((u16*)outv)[off] = f2bf(v);
        else    ((float*)outv)[off] = v;
    }
}

// ---------------------------------------------------------------------------
extern "C" void kernel_launch(void* const* d_in, const int* in_sizes, int n_in,
                              void* d_out, int out_size, void* d_ws, size_t ws_size,
                              hipStream_t stream) {
    static const int exp_sizes[27] = {
        128000, 128000, 128000, 128000, 128000,
        128000, 128000, 128000, 128000,
        16384000,
        128128, 13056, 13056, 256, 128,
        65536, 128, 16384, 128, 16384, 128,
        32768, 128, 32768, 128, 65536, 128
    };
    bool sizes_ok = (n_in == 27) && (out_size == 32768);
    if (sizes_ok)
        for (int i = 0; i < 27; ++i)
            if (in_sizes[i] != exp_sizes[i]) { sizes_ok = false; break; }
    if (!sizes_ok) {
        dimkt_sentinel<<<dim3(128), dim3(256), 0, stream>>>((u16*)d_out, (u16)0xC080); // -4.0
        return;
    }
    const size_t WS_NEED = 724480;                       // f32 tables
    const size_t WS_FB   = WS_NEED + 32768000u;          // + INP16 (proven tier, R6)
    if (ws_size < WS_FB) {
        dimkt_sentinel<<<dim3(128), dim3(256), 0, stream>>>((u16*)d_out, (u16)0x4110); // 9.0
        return;
    }
    const size_t WS_PK   = WS_NEED + 65536000u;          // INPZ6T u32
    const size_t WS_FAST = WS_PK + 32768000u + 131072u;  // + qe16 + W1bf
    const int pk   = (ws_size >= WS_PK) ? 1 : 0;
    const int fast = (ws_size >= WS_FAST) ? 1 : 0;

    const int* c   = (const int*)d_in[1];
    const int* sd  = (const int*)d_in[2];
    const int* qd  = (const int*)d_in[3];
    const int* a   = (const int*)d_in[4];
    const void* q_emb = d_in[9];
    const void* c_tab = d_in[10];
    const void* sd_tab = d_in[11];
    const void* qd_tab = d_in[12];
    const void* a_tab = d_in[13];
    const void* knowledge = d_in[14];
    const void* W1 = d_in[15]; const void* b1 = d_in[16];
    const void* W2 = d_in[17]; const void* b2 = d_in[18];
    const void* W3 = d_in[19]; const void* b3 = d_in[20];
    const void* W4 = d_in[21]; const void* b4 = d_in[22];
    const void* W5 = d_in[23]; const void* b5 = d_in[24];
    const void* W6 = d_in[25]; const void* b6 = d_in[26];

    float* wsf = (float*)d_ws;
    float* cW1p = wsf;                 // 1001*128
    float* sdQ  = wsf + 128128;        // 102*256
    float* qdQ  = wsf + 154240;        // 102*256
    float* aW6p = wsf + 180352;        // 2*128 (+b6)
    float* c4t  = wsf + 180608;        // 2*128 (+b4)
    float* c5t  = wsf + 180864;        // 2*128 (+b5)
    u16* INP16  = (u16*)((char*)d_ws + WS_NEED);   // FB tier payload
    u32* INPZ6T = (u32*)((char*)d_ws + WS_NEED);   // PK tier payload (same slot)
    u16* qe16   = (u16*)((char*)d_ws + WS_PK);
    u16* W1b    = (u16*)((char*)d_ws + WS_PK + 32768000u);

    dimkt_tabs<<<dim3(1415), dim3(128), 0, stream>>>(
        q_emb, c_tab, sd_tab, qd_tab, a_tab, W1, W4, W5, W6, b4, b5, b6,
        cW1p, sdQ, qdQ, aW6p, c4t, c5t);

    if (fast) {
        dimkt_qe16<<<dim3(8000), dim3(256), 0, stream>>>((const float*)q_emb, qe16);
        dimkt_w1bf<<<dim3(256), dim3(256), 0, stream>>>(W1, q_emb, W1b);
    }

    dimkt_inp<<<dim3(500, 16), dim3(64), 0, stream>>>(
        q_emb, qe16, W1b, fast, W1, b1, c, sd, qd, a,
        cW1p, sdQ, qdQ, aW6p, INP16, INPZ6T, pk);

    if (pk) {
        dimkt_scan_pk<true><<<dim3(16), dim3(512), 0, stream>>>(
            q_emb, INPZ6T, a, W2, b2, W3, b3, W4, W5, W6, knowledge, c4t, c5t, d_out);
        dimkt_scan_pk<false><<<dim3(16), dim3(512), 0, stream>>>(
            q_emb, INPZ6T, a, W2, b2, W3, b3, W4, W5, W6, knowledge, c4t, c5t, d_out);
    } else {
        constexpr int DYN_BYTES = 2 * 102 * 130 * 2 + 2 * 132 * 4;   // 54,096 B
        hipFuncSetAttribute(reinterpret_cast<const void*>(&dimkt_scan_fb<true>),
                            hipFuncAttributeMaxDynamicSharedMemorySize, DYN_BYTES);
        hipFuncSetAttribute(reinterpret_cast<const void*>(&dimkt_scan_fb<false>),
                            hipFuncAttributeMaxDynamicSharedMemorySize, DYN_BYTES);
        dimkt_scan_fb<true><<<dim3(16), dim3(512), DYN_BYTES, stream>>>(
            q_emb, INP16, c, sd, qd, a, W2, b2, W3, b3, W4, W5, W6, knowledge,
            sdQ, qdQ, aW6p, c4t, c5t, d_out);
        dimkt_scan_fb<false><<<dim3(16), dim3(512), DYN_BYTES, stream>>>(
            q_emb, INP16, c, sd, qd, a, W2, b2, W3, b3, W4, W5, W6, knowledge,
            sdQ, qdQ, aW6p, c4t, c5t, d_out);
    }
}

// Round 10
// 909.270 us; speedup vs baseline: 1.0583x; 1.0583x over previous
//
#include <hip/hip_runtime.h>

typedef unsigned short u16;
typedef unsigned int u32;
typedef short bf16x8 __attribute__((ext_vector_type(8)));
typedef float f32x4 __attribute__((ext_vector_type(4)));

#define S_LEN 500
#define NB 256
#define EDIM 128

__device__ __forceinline__ float bf2f(u16 u) { return __uint_as_float(((u32)u) << 16); }
__device__ __forceinline__ u16 f2bf(float f) {
    u32 x = __float_as_uint(f);
    x += 0x7FFFu + ((x >> 16) & 1u);   // round-to-nearest-even
    return (u16)(x >> 16);
}
// HW packed f32->bf16 (RNE, matches f2bf): 1 inst for 2 values. lo->bits[15:0].
__device__ __forceinline__ u32 cvtpk(float lo, float hi) {
    u32 r;
    asm("v_cvt_pk_bf16_f32 %0, %1, %2" : "=v"(r) : "v"(lo), "v"(hi));
    return r;
}
__device__ __forceinline__ float fexp(float x) { return __builtin_amdgcn_exp2f(x * 1.44269504089f); }
__device__ __forceinline__ float frcp(float x) { return __builtin_amdgcn_rcpf(x); }
__device__ __forceinline__ float sigm(float x) { return frcp(1.0f + fexp(-x)); }
__device__ __forceinline__ float tanh_(float x) { return 1.0f - 2.0f * frcp(1.0f + fexp(2.0f * x)); }
__device__ __forceinline__ int iclamp(int v, int hi) { return v < 0 ? 0 : (v > hi ? hi : v); }

// ---------------------------------------------------------------------------
// R1-proven workgroup sync: lane-0 atomicAdd on an LDS counter + broadcast
// poll. Measured FASTER than raw s_barrier on this kernel (1490 vs 1878 us)
// -- staggered release naturally de-synchronizes the 2 waves/SIMD bursts.
// ---------------------------------------------------------------------------
__device__ __forceinline__ void wgsync(volatile int* c, int target) {
    __asm__ volatile("s_waitcnt lgkmcnt(0)" ::: "memory");  // prior LDS writes done
    if ((threadIdx.x & 63) == 0) atomicAdd((int*)c, 1);
    while (*c < target) {}
    __asm__ volatile("" ::: "memory");
}

// ---------------------------------------------------------------------------
// Runtime float-dtype detection from q_embedding bit patterns (wave-uniform).
// ---------------------------------------------------------------------------
__device__ __forceinline__ bool detect_bf16(const void* q) {
    const u16* w = (const u16*)q;
    int plaus = 0;
#pragma unroll 1
    for (int i = 0; i < 64; ++i) {
        const u16 v = w[2 * i];
        const int e = (v >> 7) & 0xFF;
        plaus += (v == 0 || (e >= 100 && e <= 130)) ? 1 : 0;
    }
    return plaus >= 48;
}
__device__ __forceinline__ float ldF(const void* p, int i, bool bf) {
    return bf ? bf2f(((const u16*)p)[i]) : ((const float*)p)[i];
}
template <bool BF>
__device__ __forceinline__ bf16x8 ldfragT(const void* p, int i) {
    if (BF) return *(const bf16x8*)((const u16*)p + i);
    const float* f = (const float*)p + i;
    bf16x8 r;
#pragma unroll
    for (int e = 0; e < 8; ++e) r[e] = (short)f2bf(f[e]);
    return r;
}
// f32 fragment loader, VECTORIZED: 2x float4 + 4x v_cvt_pk_bf16_f32 (RNE,
// bit-identical to f2bf elementwise). Replaces the old 8-scalar-load path
// and the separate qe16/w1bf conversion kernels.
__device__ __forceinline__ bf16x8 ldfrag8f(const float* f) {
    const float4 a = *(const float4*)f;
    const float4 b = *(const float4*)(f + 4);
    union { u32 u[4]; bf16x8 v; } r;
    r.u[0] = cvtpk(a.x, a.y);
    r.u[1] = cvtpk(a.z, a.w);
    r.u[2] = cvtpk(b.x, b.y);
    r.u[3] = cvtpk(b.z, b.w);
    return r.v;
}

__global__ void dimkt_sentinel(u16* __restrict__ out, u16 val) {
    out[blockIdx.x * 256 + threadIdx.x] = val;
}

// ---------------------------------------------------------------------------
// K0: tiny gather-table precompute. Layout (per-col scalar):
//   cW1p[cx*128 + col] ; sdQ/qdQ[x*256 + col*2 + {0:W1,1:W6}]
//   aW6p[ax*128 + col] (+b6) ; c4t/c5t[ax*128 + col] (+b4/+b5)
// ---------------------------------------------------------------------------
__global__ void dimkt_tabs(const void* __restrict__ q_emb,
                           const void* __restrict__ c_tab, const void* __restrict__ sd_tab,
                           const void* __restrict__ qd_tab, const void* __restrict__ a_tab,
                           const void* __restrict__ W1, const void* __restrict__ W4,
                           const void* __restrict__ W5, const void* __restrict__ W6,
                           const void* __restrict__ b4, const void* __restrict__ b5,
                           const void* __restrict__ b6,
                           float* __restrict__ cW1p, float* __restrict__ sdQ,
                           float* __restrict__ qdQ, float* __restrict__ aW6p,
                           float* __restrict__ c4t, float* __restrict__ c5t) {
    const bool bf = detect_bf16(q_emb);
    __shared__ float src[128];
    const int r = blockIdx.x, n = threadIdx.x;
    const void* srcp; const void* W; const void* bias = nullptr;
    int soff, koff, ld, oidx; float* outp; bool mask;
    if (r < 1001)      { srcp = c_tab;  soff = r * 128;               W = W1; koff = 128; ld = 512; outp = cW1p; oidx = r * 128 + n;           mask = (r == 0); }
    else if (r < 1103) { int rr = r - 1001; srcp = sd_tab; soff = rr * 128; W = W1; koff = 256; ld = 512; outp = sdQ;  oidx = rr * 256 + n * 2;     mask = (rr == 0); }
    else if (r < 1205) { int rr = r - 1103; srcp = qd_tab; soff = rr * 128; W = W1; koff = 384; ld = 512; outp = qdQ;  oidx = rr * 256 + n * 2;     mask = (rr == 0); }
    else if (r < 1307) { int rr = r - 1205; srcp = sd_tab; soff = rr * 128; W = W6; koff = 256; ld = 512; outp = sdQ;  oidx = rr * 256 + n * 2 + 1; mask = (rr == 0); }
    else if (r < 1409) { int rr = r - 1307; srcp = qd_tab; soff = rr * 128; W = W6; koff = 384; ld = 512; outp = qdQ;  oidx = rr * 256 + n * 2 + 1; mask = (rr == 0); }
    else if (r < 1411) { int rr = r - 1409; srcp = a_tab;  soff = rr * 128; W = W6; koff = 128; ld = 512; outp = aW6p; oidx = rr * 128 + n;         bias = b6; mask = false; }
    else if (r < 1413) { int rr = r - 1411; srcp = a_tab;  soff = rr * 128; W = W4; koff = 128; ld = 256; outp = c4t;  oidx = rr * 128 + n;         bias = b4; mask = false; }
    else               { int rr = r - 1413; srcp = a_tab;  soff = rr * 128; W = W5; koff = 128; ld = 256; outp = c5t;  oidx = rr * 128 + n;         bias = b5; mask = false; }
    src[n] = ldF(srcp, soff + n, bf);
    __syncthreads();
    float acc = 0.f;
    if (!mask) {
        if (bf) {
            const u16* Wp = (const u16*)W + n * ld + koff;
#pragma unroll 4
            for (int k = 0; k < 128; k += 8) {
                const ushort4 wa = *(const ushort4*)(Wp + k);
                const ushort4 wb = *(const ushort4*)(Wp + k + 4);
                acc += src[k] * bf2f(wa.x) + src[k + 1] * bf2f(wa.y)
                     + src[k + 2] * bf2f(wa.z) + src[k + 3] * bf2f(wa.w)
                     + src[k + 4] * bf2f(wb.x) + src[k + 5] * bf2f(wb.y)
                     + src[k + 6] * bf2f(wb.z) + src[k + 7] * bf2f(wb.w);
            }
        } else {
            const float* Wp = (const float*)W + n * ld + koff;
#pragma unroll 4
            for (int k = 0; k < 128; k += 4) {
                const float4 w4 = *(const float4*)(Wp + k);
                acc += src[k] * w4.x + src[k + 1] * w4.y + src[k + 2] * w4.z + src[k + 3] * w4.w;
            }
        }
        if (bias) acc += ldF(bias, n, bf);
    }
    outp[oidx] = acc;
}

// ---------------------------------------------------------------------------
// K1: INP(+Z6) precompute. pk=1: store u32 {inp(bf16 lo), z6(bf16 hi)} in
// the R8-PROVEN layout INPZ6T[(t*128+col)*256 + row] (R9's block-coalesced
// variant regressed the scan 631->652 us: the scan is latency-bound and the
// scattered per-lane lines give MORE memory-level parallelism, not less).
// f32 inputs converted INLINE with vectorized float4+cvt_pk loads (replaces
// the qe16/w1bf kernels entirely). pk=0: R6-style bf16 INP16 row-major.
// ---------------------------------------------------------------------------
__global__ void dimkt_inp(const void* __restrict__ q_emb,
                          const void* __restrict__ W1, const void* __restrict__ b1,
                          const int* __restrict__ cI, const int* __restrict__ sI,
                          const int* __restrict__ qI, const int* __restrict__ aI,
                          const float* __restrict__ cW1p, const float* __restrict__ sdQ,
                          const float* __restrict__ qdQ, const float* __restrict__ aW6p,
                          u16* __restrict__ INP16, u32* __restrict__ INPZ6T, const int pk) {
    const bool bf = detect_bf16(q_emb);
    const int t = blockIdx.x, rc = blockIdx.y;
    const int lane = threadIdx.x, quad = lane >> 4, l15 = lane & 15;
    bf16x8 ae[4];
#pragma unroll
    for (int ks = 0; ks < 4; ++ks) {
        const int off = ((rc * 16 + l15) * S_LEN + t) * EDIM + ks * 32 + quad * 8;
        ae[ks] = bf ? *(const bf16x8*)((const u16*)q_emb + off)
                    : ldfrag8f((const float*)q_emb + off);
    }
    int cx[4], sx[4], qx[4], ax[4];
#pragma unroll
    for (int i = 0; i < 4; ++i) {
        const int off = (rc * 16 + quad * 4 + i) * S_LEN + t;
        cx[i] = iclamp(cI[off], 1000);
        sx[i] = iclamp(sI[off], 101);
        qx[i] = iclamp(qI[off], 101);
        ax[i] = iclamp(aI[off], 1);
    }
#pragma unroll 1
    for (int ct = 0; ct < 8; ++ct) {
        const int colc = ct * 16 + l15;
        bf16x8 w[4];
#pragma unroll
        for (int ks = 0; ks < 4; ++ks) {
            const int woff = colc * 512 + ks * 32 + quad * 8;
            w[ks] = bf ? *(const bf16x8*)((const u16*)W1 + woff)
                       : ldfrag8f((const float*)W1 + woff);
        }
        const float b1c = ldF(b1, colc, bf);
        f32x4 acc; float z6v[4];
#pragma unroll
        for (int i = 0; i < 4; ++i) {
            const float2 sgp = *(const float2*)(sdQ + sx[i] * 256 + colc * 2);
            const float2 qgp = *(const float2*)(qdQ + qx[i] * 256 + colc * 2);
            acc[i] = b1c + cW1p[cx[i] * 128 + colc] + sgp.x + qgp.x;
            z6v[i] = pk ? (aW6p[ax[i] * 128 + colc] + sgp.y + qgp.y) : 0.f;
        }
#pragma unroll
        for (int ks = 0; ks < 4; ++ks)
            acc = __builtin_amdgcn_mfma_f32_16x16x32_bf16(ae[ks], w[ks], acc, 0, 0, 0);
        if (pk) {
            uint4 st;
            st.x = cvtpk(acc[0], z6v[0]); st.y = cvtpk(acc[1], z6v[1]);
            st.z = cvtpk(acc[2], z6v[2]); st.w = cvtpk(acc[3], z6v[3]);
            *(uint4*)(INPZ6T + ((size_t)t * 128 + colc) * 256 + rc * 16 + quad * 4) = st;
        } else {
#pragma unroll
            for (int i = 0; i < 4; ++i)
                INP16[((size_t)t * 256 + rc * 16 + quad * 4 + i) * 128 + colc] = f2bf(acc[i]);
        }
    }
}

// ---------------------------------------------------------------------------
// K2-PK: fused 500-step scan, packed-input form. 16 WGs x 512 threads.
// EXACT R8 form (proven 631 us): XOR-swizzled LDS state buffers, peeled
// final step -> affine pointer-increment streams, un-split 4-deep MFMA
// chains, per-step 4 aI dword loads (R9's aBits/coalesced-pz regressed).
// ---------------------------------------------------------------------------
template <bool BF>
__global__ __launch_bounds__(512, 2) void dimkt_scan_pk(
    const void* __restrict__ q_emb, const u32* __restrict__ INPZ6T,
    const int* __restrict__ aI,
    const void* __restrict__ W2, const void* __restrict__ b2,
    const void* __restrict__ W3, const void* __restrict__ b3,
    const void* __restrict__ W4, const void* __restrict__ W5,
    const void* __restrict__ W6, const void* __restrict__ knowledge,
    const float* __restrict__ c4t, const float* __restrict__ c5t,
    void* __restrict__ outv) {
    if (detect_bf16(q_emb) != BF) return;   // wrong specialization: uniform exit
    __shared__ __align__(16) u16 kbuf[16][136];
    __shared__ __align__(16) u16 qqbuf[16][136];
    __shared__ __align__(16) u16 sdbuf[16][136];
    __shared__ int sctr;

    const int tid = threadIdx.x;
    const int wv = tid >> 6, lane = tid & 63;
    const int quad = lane >> 4, l15 = lane & 15;
    const int b0 = blockIdx.x * 16;
    const int col = wv * 16 + l15;
    const int quadX = quad ^ (l15 >> 2);   // read-side swizzled chunk index
    const int wcolX = col ^ (quad << 3);   // write-side swizzled column

    // ---- stationary weight fragments (registers, 500-step resident) ----
    bf16x8 fW2[4], fW3[4], fW4[4], fW5[4], fW6[4];
#pragma unroll
    for (int ks = 0; ks < 4; ++ks) {
        const int ko = ks * 32 + quad * 8;
        fW2[ks] = ldfragT<BF>(W2, col * 128 + ko);
        fW3[ks] = ldfragT<BF>(W3, col * 128 + ko);
        fW4[ks] = ldfragT<BF>(W4, col * 256 + ko);   // W4[:, :128]
        fW5[ks] = ldfragT<BF>(W5, col * 256 + ko);   // W5[:, :128]
        fW6[ks] = ldfragT<BF>(W6, col * 512 + ko);   // W6[:, :128]
    }
    const float b2v = ldF(b2, col, BF);
    const float b3v = ldF(b3, col, BF);
    const float c4_0 = c4t[col], c4_1 = c4t[128 + col];
    const float c5_0 = c5t[col], c5_1 = c5t[128 + col];

    const u32* pzBase = INPZ6T + (size_t)col * 256 + b0 + quad * 4;
    const int* aBase = aI + (b0 + quad * 4) * S_LEN;

    // ---- t=0 init ----
    float kold[4], z6c[4], g[4];
    int ac[4];
    {
        const float k0 = ldF(knowledge, col, BF);
        const u16 k0b = f2bf(k0);
        const uint4 pz0 = *(const uint4*)pzBase;
        const u32 pzv[4] = {pz0.x, pz0.y, pz0.z, pz0.w};
        if (tid == 0) sctr = 0;
#pragma unroll
        for (int i = 0; i < 4; ++i) {
            ac[i] = iclamp(aBase[i * S_LEN], 1);
            z6c[i] = __uint_as_float(pzv[i] & 0xFFFF0000u);
            const float inp0 = __uint_as_float(pzv[i] << 16);
            kold[i] = k0;
            kbuf[quad * 4 + i][wcolX] = k0b;
            qqbuf[quad * 4 + i][wcolX] = f2bf(k0 - inp0);
        }
    }
    __syncthreads();   // one real barrier pre-loop

    const u32* pzP = pzBase + 32768;   // {inp,z6} stream, t+1
    const int* aP = aBase + 1;         // a stream, t+1
    int bar = 0;
#pragma unroll 1
    for (int t = 0; t < S_LEN - 1; ++t) {
        // ---- prefetch t+1: a-bits + packed {inp,z6} (pointer-increment) ----
        int an[4];
#pragma unroll
        for (int i = 0; i < 4; ++i) an[i] = iclamp(aP[i * S_LEN], 1);
        const uint4 pzN = *(const uint4*)pzP;
        aP += 1; pzP += 32768;

        // ---- phase B: Y2/Y3 on qq, Y6 on k; sdft -> LDS ----
        bf16x8 aq[4], ak[4];
#pragma unroll
        for (int ks = 0; ks < 4; ++ks) {
            aq[ks] = *(const bf16x8*)&qqbuf[l15][ks * 32 + quadX * 8];
            ak[ks] = *(const bf16x8*)&kbuf[l15][ks * 32 + quadX * 8];
        }
        f32x4 Y2 = (f32x4){b2v, b2v, b2v, b2v};
        f32x4 Y3 = (f32x4){b3v, b3v, b3v, b3v};
        f32x4 Y6 = (f32x4){z6c[0], z6c[1], z6c[2], z6c[3]};
#pragma unroll
        for (int ks = 0; ks < 4; ++ks) {
            Y2 = __builtin_amdgcn_mfma_f32_16x16x32_bf16(aq[ks], fW2[ks], Y2, 0, 0, 0);
            Y3 = __builtin_amdgcn_mfma_f32_16x16x32_bf16(aq[ks], fW3[ks], Y3, 0, 0, 0);
            Y6 = __builtin_amdgcn_mfma_f32_16x16x32_bf16(ak[ks], fW6[ks], Y6, 0, 0, 0);
        }
        float sdv[4];
#pragma unroll
        for (int i = 0; i < 4; ++i) sdv[i] = sigm(Y2[i]) * tanh_(Y3[i]);
        {
            const u32 s01 = cvtpk(sdv[0], sdv[1]), s23 = cvtpk(sdv[2], sdv[3]);
            sdbuf[quad * 4 + 0][wcolX] = (u16)s01;
            sdbuf[quad * 4 + 1][wcolX] = (u16)(s01 >> 16);
            sdbuf[quad * 4 + 2][wcolX] = (u16)s23;
            sdbuf[quad * 4 + 3][wcolX] = (u16)(s23 >> 16);
        }
        bar += 8; wgsync(&sctr, bar);

        // ---- phase C: Y4/Y5 on sdft; g; k update; write k/qq for t+1 ----
        bf16x8 as[4];
#pragma unroll
        for (int ks = 0; ks < 4; ++ks)
            as[ks] = *(const bf16x8*)&sdbuf[l15][ks * 32 + quadX * 8];
#pragma unroll
        for (int i = 0; i < 4; ++i) g[i] = sigm(Y6[i]);
        f32x4 Y4 = (f32x4){ac[0] ? c4_1 : c4_0, ac[1] ? c4_1 : c4_0,
                           ac[2] ? c4_1 : c4_0, ac[3] ? c4_1 : c4_0};
        f32x4 Y5 = (f32x4){ac[0] ? c5_1 : c5_0, ac[1] ? c5_1 : c5_0,
                           ac[2] ? c5_1 : c5_0, ac[3] ? c5_1 : c5_0};
#pragma unroll
        for (int ks = 0; ks < 4; ++ks) {
            Y4 = __builtin_amdgcn_mfma_f32_16x16x32_bf16(as[ks], fW4[ks], Y4, 0, 0, 0);
            Y5 = __builtin_amdgcn_mfma_f32_16x16x32_bf16(as[ks], fW5[ks], Y5, 0, 0, 0);
        }
        const u32 pzv[4] = {pzN.x, pzN.y, pzN.z, pzN.w};
        float knA[4], qqA[4];
#pragma unroll
        for (int i = 0; i < 4; ++i) {
            const float pk = sigm(Y4[i]) * tanh_(Y5[i]);
            const float kn = g[i] * kold[i] + (1.0f - g[i]) * pk;
            kold[i] = kn; knA[i] = kn;
            qqA[i] = kn - __uint_as_float(pzv[i] << 16);    // qq_{t+1} = k - inp_{t+1}
        }
        {
            const u32 k01 = cvtpk(knA[0], knA[1]), k23 = cvtpk(knA[2], knA[3]);
            const u32 q01 = cvtpk(qqA[0], qqA[1]), q23 = cvtpk(qqA[2], qqA[3]);
            kbuf[quad * 4 + 0][wcolX] = (u16)k01;
            kbuf[quad * 4 + 1][wcolX] = (u16)(k01 >> 16);
            kbuf[quad * 4 + 2][wcolX] = (u16)k23;
            kbuf[quad * 4 + 3][wcolX] = (u16)(k23 >> 16);
            qqbuf[quad * 4 + 0][wcolX] = (u16)q01;
            qqbuf[quad * 4 + 1][wcolX] = (u16)(q01 >> 16);
            qqbuf[quad * 4 + 2][wcolX] = (u16)q23;
            qqbuf[quad * 4 + 3][wcolX] = (u16)(q23 >> 16);
        }
        // ---- rotate: z6/ac for t+1 (straight from packed load) ----
#pragma unroll
        for (int i = 0; i < 4; ++i) {
            z6c[i] = __uint_as_float(pzv[i] & 0xFFFF0000u);
            ac[i] = an[i];
        }
        bar += 8; wgsync(&sctr, bar);
    }

    // ---- peeled final step (t = S_LEN-1): no prefetch, no next-state
    //      writes, no trailing sync (epilogue is thread-local) ----
    {
        bf16x8 aq[4], ak[4];
#pragma unroll
        for (int ks = 0; ks < 4; ++ks) {
            aq[ks] = *(const bf16x8*)&qqbuf[l15][ks * 32 + quadX * 8];
            ak[ks] = *(const bf16x8*)&kbuf[l15][ks * 32 + quadX * 8];
        }
        f32x4 Y2 = (f32x4){b2v, b2v, b2v, b2v};
        f32x4 Y3 = (f32x4){b3v, b3v, b3v, b3v};
        f32x4 Y6 = (f32x4){z6c[0], z6c[1], z6c[2], z6c[3]};
#pragma unroll
        for (int ks = 0; ks < 4; ++ks) {
            Y2 = __builtin_amdgcn_mfma_f32_16x16x32_bf16(aq[ks], fW2[ks], Y2, 0, 0, 0);
            Y3 = __builtin_amdgcn_mfma_f32_16x16x32_bf16(aq[ks], fW3[ks], Y3, 0, 0, 0);
            Y6 = __builtin_amdgcn_mfma_f32_16x16x32_bf16(ak[ks], fW6[ks], Y6, 0, 0, 0);
        }
        float sdv[4];
#pragma unroll
        for (int i = 0; i < 4; ++i) sdv[i] = sigm(Y2[i]) * tanh_(Y3[i]);
        {
            const u32 s01 = cvtpk(sdv[0], sdv[1]), s23 = cvtpk(sdv[2], sdv[3]);
            sdbuf[quad * 4 + 0][wcolX] = (u16)s01;
            sdbuf[quad * 4 + 1][wcolX] = (u16)(s01 >> 16);
            sdbuf[quad * 4 + 2][wcolX] = (u16)s23;
            sdbuf[quad * 4 + 3][wcolX] = (u16)(s23 >> 16);
        }
        bar += 8; wgsync(&sctr, bar);

        bf16x8 as[4];
#pragma unroll
        for (int ks = 0; ks < 4; ++ks)
            as[ks] = *(const bf16x8*)&sdbuf[l15][ks * 32 + quadX * 8];
#pragma unroll
        for (int i = 0; i < 4; ++i) g[i] = sigm(Y6[i]);
        f32x4 Y4 = (f32x4){ac[0] ? c4_1 : c4_0, ac[1] ? c4_1 : c4_0,
                           ac[2] ? c4_1 : c4_0, ac[3] ? c4_1 : c4_0};
        f32x4 Y5 = (f32x4){ac[0] ? c5_1 : c5_0, ac[1] ? c5_1 : c5_0,
                           ac[2] ? c5_1 : c5_0, ac[3] ? c5_1 : c5_0};
#pragma unroll
        for (int ks = 0; ks < 4; ++ks) {
            Y4 = __builtin_amdgcn_mfma_f32_16x16x32_bf16(as[ks], fW4[ks], Y4, 0, 0, 0);
            Y5 = __builtin_amdgcn_mfma_f32_16x16x32_bf16(as[ks], fW5[ks], Y5, 0, 0, 0);
        }
#pragma unroll
        for (int i = 0; i < 4; ++i) {
            const float pk = sigm(Y4[i]) * tanh_(Y5[i]);
            kold[i] = g[i] * kold[i] + (1.0f - g[i]) * pk;
        }
    }

    // ---- epilogue: out = sigmoid(k_final), [B][E], dtype matches input ----
#pragma unroll
    for (int i = 0; i < 4; ++i) {
        const int row = quad * 4 + i;
        const float v = sigm(kold[i]);
        const int off = (b0 + row) * EDIM + col;
        if (BF) ((u16*)outv)[off] = f2bf(v);
        else    ((float*)outv)[off] = v;
    }
}

// ---------------------------------------------------------------------------
// K2-FB: R6 scan, verbatim (fallback when ws can't hold INPZ6T).
// ---------------------------------------------------------------------------
template <bool BF>
__global__ __launch_bounds__(512, 2) void dimkt_scan_fb(
    const void* __restrict__ q_emb, const u16* __restrict__ INP16,
    const int* __restrict__ cI, const int* __restrict__ sI,
    const int* __restrict__ qI, const int* __restrict__ aI,
    const void* __restrict__ W2, const void* __restrict__ b2,
    const void* __restrict__ W3, const void* __restrict__ b3,
    const void* __restrict__ W4, const void* __restrict__ W5,
    const void* __restrict__ W6, const void* __restrict__ knowledge,
    const float* __restrict__ sdQ, const float* __restrict__ qdQ,
    const float* __restrict__ aW6p, const float* __restrict__ c4t,
    const float* __restrict__ c5t, void* __restrict__ outv) {
    if (detect_bf16(q_emb) != BF) return;
    __shared__ __align__(16) u16 kbuf[16][136];
    __shared__ __align__(16) u16 qqbuf[16][136];
    __shared__ __align__(16) u16 sdbuf[16][136];
    __shared__ u32 idxL[16][S_LEN];
    __shared__ int sctr;
    extern __shared__ __align__(16) u16 dynLDS[];
    u16* sdT = dynLDS;
    u16* qdT = dynLDS + 102 * 130;
    float* aW6L = (float*)(dynLDS + 2 * 102 * 130);

    const int tid = threadIdx.x;
    const int wv = tid >> 6, lane = tid & 63;
    const int quad = lane >> 4, l15 = lane & 15;
    const int b0 = blockIdx.x * 16;
    const int col = wv * 16 + l15;
    const int col2 = col * 2;

    bf16x8 fW2[4], fW3[4], fW4[4], fW5[4], fW6[4];
#pragma unroll
    for (int ks = 0; ks < 4; ++ks) {
        const int ko = ks * 32 + quad * 8;
        fW2[ks] = ldfragT<BF>(W2, col * 128 + ko);
        fW3[ks] = ldfragT<BF>(W3, col * 128 + ko);
        fW4[ks] = ldfragT<BF>(W4, col * 256 + ko);
        fW5[ks] = ldfragT<BF>(W5, col * 256 + ko);
        fW6[ks] = ldfragT<BF>(W6, col * 512 + ko);
    }
    const float b2v = ldF(b2, col, BF);
    const float b3v = ldF(b3, col, BF);
    const float c4_0 = c4t[col], c4_1 = c4t[128 + col];
    const float c5_0 = c5t[col], c5_1 = c5t[128 + col];

#pragma unroll 1
    for (int r = 0; r < 16; ++r)
#pragma unroll 1
        for (int t = tid; t < S_LEN; t += 512) {
            const int off = (b0 + r) * S_LEN + t;
            idxL[r][t] = (u32)iclamp(cI[off], 1000)
                       | ((u32)iclamp(sI[off], 101) << 10)
                       | ((u32)iclamp(qI[off], 101) << 17)
                       | ((u32)iclamp(aI[off], 1) << 24);
        }
#pragma unroll 1
    for (int v = tid; v < 102 * 128; v += 512) {
        const int sx = v >> 7, cc = v & 127;
        sdT[sx * 130 + cc] = f2bf(sdQ[sx * 256 + cc * 2 + 1]);
        qdT[sx * 130 + cc] = f2bf(qdQ[sx * 256 + cc * 2 + 1]);
    }
    if (tid < 256) {
        const int rr = tid >> 7, cc = tid & 127;
        aW6L[rr * 132 + cc] = aW6p[rr * 128 + cc];
    }
    if (tid == 0) sctr = 0;
    __syncthreads();

    float kold[4], z6c[4], g[4];
    int ac[4];
    {
        const float k0 = ldF(knowledge, col, BF);
        const u16 k0b = f2bf(k0);
#pragma unroll
        for (int i = 0; i < 4; ++i) {
            const u32 p = idxL[quad * 4 + i][0];
            const int sx = (p >> 10) & 127, qx = (p >> 17) & 127, ax = (p >> 24) & 1;
            ac[i] = ax;
            const float2 sgp = *(const float2*)(sdQ + sx * 256 + col2);
            const float2 qgp = *(const float2*)(qdQ + qx * 256 + col2);
            z6c[i] = aW6p[ax * 128 + col] + sgp.y + qgp.y;
            const float inp0 = bf2f(INP16[(size_t)(b0 + quad * 4 + i) * 128 + col]);
            kold[i] = k0;
            kbuf[quad * 4 + i][col] = k0b;
            qqbuf[quad * 4 + i][col] = f2bf(k0 - inp0);
        }
    }
    u32 pk4[4];
#pragma unroll
    for (int i = 0; i < 4; ++i) pk4[i] = idxL[quad * 4 + i][1];
    __syncthreads();

    int bar = 0;
#pragma unroll 1
    for (int t = 0; t < S_LEN; ++t) {
        const int tf2 = (t + 2 < S_LEN) ? t + 2 : S_LEN - 1;
        const int tp = (t + 1 < S_LEN) ? t + 1 : S_LEN - 1;
        int an[4];
        u16 inpN[4];
        float sw6[4], qw6[4], agv[4];
#pragma unroll
        for (int i = 0; i < 4; ++i) {
            const u32 p = pk4[i];
            const int sx = (p >> 10) & 127, qx = (p >> 17) & 127;
            an[i] = (p >> 24) & 1;
            inpN[i] = INP16[((size_t)tp * 256 + b0 + quad * 4 + i) * 128 + col];
            sw6[i] = bf2f(sdT[sx * 130 + col]);
            qw6[i] = bf2f(qdT[qx * 130 + col]);
            agv[i] = aW6L[an[i] * 132 + col];
        }
#pragma unroll
        for (int i = 0; i < 4; ++i) pk4[i] = idxL[quad * 4 + i][tf2];

        bf16x8 aq[4], ak[4];
#pragma unroll
        for (int ks = 0; ks < 4; ++ks) {
            aq[ks] = *(const bf16x8*)&qqbuf[l15][ks * 32 + quad * 8];
            ak[ks] = *(const bf16x8*)&kbuf[l15][ks * 32 + quad * 8];
        }
        f32x4 Y2a = (f32x4){b2v, b2v, b2v, b2v}, Y2b = (f32x4){0.f, 0.f, 0.f, 0.f};
        f32x4 Y3a = (f32x4){b3v, b3v, b3v, b3v}, Y3b = (f32x4){0.f, 0.f, 0.f, 0.f};
        f32x4 Y6a = (f32x4){z6c[0], z6c[1], z6c[2], z6c[3]}, Y6b = (f32x4){0.f, 0.f, 0.f, 0.f};
        Y2a = __builtin_amdgcn_mfma_f32_16x16x32_bf16(aq[0], fW2[0], Y2a, 0, 0, 0);
        Y3a = __builtin_amdgcn_mfma_f32_16x16x32_bf16(aq[0], fW3[0], Y3a, 0, 0, 0);
        Y6a = __builtin_amdgcn_mfma_f32_16x16x32_bf16(ak[0], fW6[0], Y6a, 0, 0, 0);
        Y2b = __builtin_amdgcn_mfma_f32_16x16x32_bf16(aq[2], fW2[2], Y2b, 0, 0, 0);
        Y3b = __builtin_amdgcn_mfma_f32_16x16x32_bf16(aq[2], fW3[2], Y3b, 0, 0, 0);
        Y6b = __builtin_amdgcn_mfma_f32_16x16x32_bf16(ak[2], fW6[2], Y6b, 0, 0, 0);
        Y2a = __builtin_amdgcn_mfma_f32_16x16x32_bf16(aq[1], fW2[1], Y2a, 0, 0, 0);
        Y3a = __builtin_amdgcn_mfma_f32_16x16x32_bf16(aq[1], fW3[1], Y3a, 0, 0, 0);
        Y6a = __builtin_amdgcn_mfma_f32_16x16x32_bf16(ak[1], fW6[1], Y6a, 0, 0, 0);
        Y2b = __builtin_amdgcn_mfma_f32_16x16x32_bf16(aq[3], fW2[3], Y2b, 0, 0, 0);
        Y3b = __builtin_amdgcn_mfma_f32_16x16x32_bf16(aq[3], fW3[3], Y3b, 0, 0, 0);
        Y6b = __builtin_amdgcn_mfma_f32_16x16x32_bf16(ak[3], fW6[3], Y6b, 0, 0, 0);
        const f32x4 Y2 = Y2a + Y2b, Y3 = Y3a + Y3b, Y6 = Y6a + Y6b;
        float sdv[4];
#pragma unroll
        for (int i = 0; i < 4; ++i) sdv[i] = sigm(Y2[i]) * tanh_(Y3[i]);
        {
            const u32 s01 = cvtpk(sdv[0], sdv[1]), s23 = cvtpk(sdv[2], sdv[3]);
            sdbuf[quad * 4 + 0][col] = (u16)s01;
            sdbuf[quad * 4 + 1][col] = (u16)(s01 >> 16);
            sdbuf[quad * 4 + 2][col] = (u16)s23;
            sdbuf[quad * 4 + 3][col] = (u16)(s23 >> 16);
        }
        bar += 8; wgsync(&sctr, bar);

        bf16x8 as[4];
#pragma unroll
        for (int ks = 0; ks < 4; ++ks)
            as[ks] = *(const bf16x8*)&sdbuf[l15][ks * 32 + quad * 8];
#pragma unroll
        for (int i = 0; i < 4; ++i) g[i] = sigm(Y6[i]);
        f32x4 Y4a = (f32x4){ac[0] ? c4_1 : c4_0, ac[1] ? c4_1 : c4_0,
                            ac[2] ? c4_1 : c4_0, ac[3] ? c4_1 : c4_0};
        f32x4 Y5a = (f32x4){ac[0] ? c5_1 : c5_0, ac[1] ? c5_1 : c5_0,
                            ac[2] ? c5_1 : c5_0, ac[3] ? c5_1 : c5_0};
        f32x4 Y4b = (f32x4){0.f, 0.f, 0.f, 0.f}, Y5b = (f32x4){0.f, 0.f, 0.f, 0.f};
        Y4a = __builtin_amdgcn_mfma_f32_16x16x32_bf16(as[0], fW4[0], Y4a, 0, 0, 0);
        Y5a = __builtin_amdgcn_mfma_f32_16x16x32_bf16(as[0], fW5[0], Y5a, 0, 0, 0);
        Y4b = __builtin_amdgcn_mfma_f32_16x16x32_bf16(as[2], fW4[2], Y4b, 0, 0, 0);
        Y5b = __builtin_amdgcn_mfma_f32_16x16x32_bf16(as[2], fW5[2], Y5b, 0, 0, 0);
        Y4a = __builtin_amdgcn_mfma_f32_16x16x32_bf16(as[1], fW4[1], Y4a, 0, 0, 0);
        Y5a = __builtin_amdgcn_mfma_f32_16x16x32_bf16(as[1], fW5[1], Y5a, 0, 0, 0);
        Y4b = __builtin_amdgcn_mfma_f32_16x16x32_bf16(as[3], fW4[3], Y4b, 0, 0, 0);
        Y5b = __builtin_amdgcn_mfma_f32_16x16x32_bf16(as[3], fW5[3], Y5b, 0, 0, 0);
        const f32x4 Y4 = Y4a + Y4b, Y5 = Y5a + Y5b;
        float knA[4], qqA[4];
#pragma unroll
        for (int i = 0; i < 4; ++i) {
            const float pk = sigm(Y4[i]) * tanh_(Y5[i]);
            const float kn = g[i] * kold[i] + (1.0f - g[i]) * pk;
            kold[i] = kn; knA[i] = kn;
            qqA[i] = kn - bf2f(inpN[i]);
        }
        {
            const u32 k01 = cvtpk(knA[0], knA[1]), k23 = cvtpk(knA[2], knA[3]);
            const u32 q01 = cvtpk(qqA[0], qqA[1]), q23 = cvtpk(qqA[2], qqA[3]);
            kbuf[quad * 4 + 0][col] = (u16)k01;
            kbuf[quad * 4 + 1][col] = (u16)(k01 >> 16);
            kbuf[quad * 4 + 2][col] = (u16)k23;
            kbuf[quad * 4 + 3][col] = (u16)(k23 >> 16);
            qqbuf[quad * 4 + 0][col] = (u16)q01;
            qqbuf[quad * 4 + 1][col] = (u16)(q01 >> 16);
            qqbuf[quad * 4 + 2][col] = (u16)q23;
            qqbuf[quad * 4 + 3][col] = (u16)(q23 >> 16);
        }
#pragma unroll
        for (int i = 0; i < 4; ++i) {
            z6c[i] = agv[i] + sw6[i] + qw6[i];
            ac[i] = an[i];
        }
        bar += 8; wgsync(&sctr, bar);
    }

#pragma unroll
    for (int i = 0; i < 4; ++i) {
        const int row = quad * 4 + i;
        const float v = sigm(kold[i]);
        const int off = (b0 + row) * EDIM + col;
        if (BF) ((u16*)outv)[off] = f2bf(v);
        else    ((float*)outv)[off] = v;
    }
}

// ---------------------------------------------------------------------------
extern "C" void kernel_launch(void* const* d_in, const int* in_sizes, int n_in,
                              void* d_out, int out_size, void* d_ws, size_t ws_size,
                              hipStream_t stream) {
    static const int exp_sizes[27] = {
        128000, 128000, 128000, 128000, 128000,
        128000, 128000, 128000, 128000,
        16384000,
        128128, 13056, 13056, 256, 128,
        65536, 128, 16384, 128, 16384, 128,
        32768, 128, 32768, 128, 65536, 128
    };
    bool sizes_ok = (n_in == 27) && (out_size == 32768);
    if (sizes_ok)
        for (int i = 0; i < 27; ++i)
            if (in_sizes[i] != exp_sizes[i]) { sizes_ok = false; break; }
    if (!sizes_ok) {
        dimkt_sentinel<<<dim3(128), dim3(256), 0, stream>>>((u16*)d_out, (u16)0xC080); // -4.0
        return;
    }
    const size_t WS_NEED = 724480;                       // f32 tables
    const size_t WS_FB   = WS_NEED + 32768000u;          // + INP16 (proven tier, R6)
    if (ws_size < WS_FB) {
        dimkt_sentinel<<<dim3(128), dim3(256), 0, stream>>>((u16*)d_out, (u16)0x4110); // 9.0
        return;
    }
    const size_t WS_PK   = WS_NEED + 65536000u;          // INPZ6T u32 (proven tier, R7/R8)
    const int pk = (ws_size >= WS_PK) ? 1 : 0;

    const int* c   = (const int*)d_in[1];
    const int* sd  = (const int*)d_in[2];
    const int* qd  = (const int*)d_in[3];
    const int* a   = (const int*)d_in[4];
    const void* q_emb = d_in[9];
    const void* c_tab = d_in[10];
    const void* sd_tab = d_in[11];
    const void* qd_tab = d_in[12];
    const void* a_tab = d_in[13];
    const void* knowledge = d_in[14];
    const void* W1 = d_in[15]; const void* b1 = d_in[16];
    const void* W2 = d_in[17]; const void* b2 = d_in[18];
    const void* W3 = d_in[19]; const void* b3 = d_in[20];
    const void* W4 = d_in[21]; const void* b4 = d_in[22];
    const void* W5 = d_in[23]; const void* b5 = d_in[24];
    const void* W6 = d_in[25]; const void* b6 = d_in[26];

    float* wsf = (float*)d_ws;
    float* cW1p = wsf;                 // 1001*128
    float* sdQ  = wsf + 128128;        // 102*256
    float* qdQ  = wsf + 154240;        // 102*256
    float* aW6p = wsf + 180352;        // 2*128 (+b6)
    float* c4t  = wsf + 180608;        // 2*128 (+b4)
    float* c5t  = wsf + 180864;        // 2*128 (+b5)
    u16* INP16  = (u16*)((char*)d_ws + WS_NEED);   // FB tier payload
    u32* INPZ6T = (u32*)((char*)d_ws + WS_NEED);   // PK tier payload (same slot)

    dimkt_tabs<<<dim3(1415), dim3(128), 0, stream>>>(
        q_emb, c_tab, sd_tab, qd_tab, a_tab, W1, W4, W5, W6, b4, b5, b6,
        cW1p, sdQ, qdQ, aW6p, c4t, c5t);

    dimkt_inp<<<dim3(500, 16), dim3(64), 0, stream>>>(
        q_emb, W1, b1, c, sd, qd, a,
        cW1p, sdQ, qdQ, aW6p, INP16, INPZ6T, pk);

    if (pk) {
        dimkt_scan_pk<true><<<dim3(16), dim3(512), 0, stream>>>(
            q_emb, INPZ6T, a, W2, b2, W3, b3, W4, W5, W6, knowledge, c4t, c5t, d_out);
        dimkt_scan_pk<false><<<dim3(16), dim3(512), 0, stream>>>(
            q_emb, INPZ6T, a, W2, b2, W3, b3, W4, W5, W6, knowledge, c4t, c5t, d_out);
    } else {
        constexpr int DYN_BYTES = 2 * 102 * 130 * 2 + 2 * 132 * 4;   // 54,096 B
        hipFuncSetAttribute(reinterpret_cast<const void*>(&dimkt_scan_fb<true>),
                            hipFuncAttributeMaxDynamicSharedMemorySize, DYN_BYTES);
        hipFuncSetAttribute(reinterpret_cast<const void*>(&dimkt_scan_fb<false>),
                            hipFuncAttributeMaxDynamicSharedMemorySize, DYN_BYTES);
        dimkt_scan_fb<true><<<dim3(16), dim3(512), DYN_BYTES, stream>>>(
            q_emb, INP16, c, sd, qd, a, W2, b2, W3, b3, W4, W5, W6, knowledge,
            sdQ, qdQ, aW6p, c4t, c5t, d_out);
        dimkt_scan_fb<false><<<dim3(16), dim3(512), DYN_BYTES, stream>>>(
            q_emb, INP16, c, sd, qd, a, W2, b2, W3, b3, W4, W5, W6, knowledge,
            sdQ, qdQ, aW6p, c4t, c5t, d_out);
    }
}